// Round 21
// baseline (1083.524 us; speedup 1.0000x reference)
//
#include <hip/hip_runtime.h>
#include <math.h>

#define BATCH 256
#define SEQ   196
#define EMB   256
#define HEADS 8
#define HDIM  32
#define NBLK  4
#define FDIM  1024
#define NQB   8
#define NCLS  10
#define MROWS (BATCH*SEQ)   // 50176 = 392*128 = 784*64 = 3136*16

typedef __attribute__((ext_vector_type(8))) short  short8;   // 8 bf16 (4 VGPRs)
typedef __attribute__((ext_vector_type(4))) float  floatx4;  // MFMA acc

// fp32 -> bf16 RNE
__device__ __forceinline__ unsigned short f2b(float f) {
    unsigned u = __builtin_bit_cast(unsigned, f);
    u += 0x7fffu + ((u >> 16) & 1u);
    return (unsigned short)(u >> 16);
}
// bf16 -> fp32
__device__ __forceinline__ float b2f(unsigned short u) {
    return __builtin_bit_cast(float, ((unsigned)u) << 16);
}

// async global->LDS, 16B per lane. LDS dest is wave-uniform base; HW adds lane*16.
__device__ __forceinline__ void gl_lds16(const void* g, void* l) {
    __builtin_amdgcn_global_load_lds(
        (const __attribute__((address_space(1))) unsigned int*)g,
        (__attribute__((address_space(3))) unsigned int*)l, 16, 0, 0);
}

// softmax scale (1/sqrt(32)) * log2(e): Q pre-scaled so scores exit the
// QK MFMA in exp2 domain.
#define QSCALE (0.17677669529663687f * 1.4426950408889634f)

// ------------------------------------------------------------------
// Positional encoding table
// ------------------------------------------------------------------
__global__ void pe_kernel(float* __restrict__ pe) {
    int s = blockIdx.x, e = threadIdx.x;
    int j2 = (e >> 1) * 2;
    float dv  = expf(-(float)j2 * (logf(10000.0f) / (float)EMB));
    float ang = (float)s * dv;
    pe[s * EMB + e] = (e & 1) ? cosf(ang) : sinf(ang);
}

// ------------------------------------------------------------------
// fp32 -> bf16 bulk convert (weights), n % 4 == 0
// ------------------------------------------------------------------
__global__ __launch_bounds__(256) void cvt_kernel(
    const float* __restrict__ src, unsigned short* __restrict__ dst, int n)
{
    int i = (blockIdx.x * 256 + threadIdx.x) * 4;
    if (i < n) {
        float4 v = *(const float4*)(src + i);
        ushort4 o;
        o.x = f2b(v.x); o.y = f2b(v.y); o.z = f2b(v.z); o.w = f2b(v.w);
        *(ushort4*)(dst + i) = o;
    }
}

// ------------------------------------------------------------------
// l1_w [NBLK][FDIM][NQB] -> l1wT [NBLK][NQB][FDIM]  (fp32)
// ------------------------------------------------------------------
__global__ __launch_bounds__(256) void l1t_kernel(
    const float* __restrict__ src, float* __restrict__ dst)
{
    int idx = blockIdx.x * 256 + threadIdx.x;   // (i*FDIM + f)*NQB + q
    int i = idx >> 13, rem = idx & 8191;
    int q = rem & 7, f = rem >> 3;
    dst[((size_t)i * NQB + q) * FDIM + f] = src[idx];
}

// ------------------------------------------------------------------
// Stage 1: conv features, one thread per (token, c). feat[MROWS][4].
// ------------------------------------------------------------------
__global__ __launch_bounds__(256) void feat_kernel(
    const float* __restrict__ x,  const float* __restrict__ qw,
    const float* __restrict__ qb, const float* __restrict__ pw,
    const float* __restrict__ pb, float* __restrict__ feat)
{
    int idx = blockIdx.x * 256 + threadIdx.x;   // < MROWS*4
    int bs = idx >> 2, c = idx & 3;
    int b  = bs / SEQ, s = bs % SEQ;
    int co = s / 49;
    int p  = (s % 49) * 4 + c;
    int hh = p / 14, ww = p % 14;

    float dw[4];
#pragma unroll
    for (int ci = 0; ci < 4; ++ci) {
        const float* xp = x + (((size_t)b * 4 + ci) * 28 + hh * 2) * 28 + ww * 2;
        dw[ci] = qb[ci] + xp[0]  * qw[ci * 4 + 0] + xp[1]  * qw[ci * 4 + 1]
                        + xp[28] * qw[ci * 4 + 2] + xp[29] * qw[ci * 4 + 3];
    }
    feat[idx] = pb[co] + pw[co * 4 + 0] * dw[0] + pw[co * 4 + 1] * dw[1]
                       + pw[co * 4 + 2] * dw[2] + pw[co * 4 + 3] * dw[3];
}

// ------------------------------------------------------------------
// Stage 2: embed + PE -> hb (bf16 stream)
// ------------------------------------------------------------------
__global__ __launch_bounds__(256) void embed2_kernel(
    const float* __restrict__ feat, const float* __restrict__ ew,
    const float* __restrict__ eb,   const float* __restrict__ pe,
    unsigned short* __restrict__ hb)
{
    __shared__ float fL[32 * 4];
    int t = threadIdx.x;
    int base = blockIdx.x * 32;

    if (t < 128) fL[t] = feat[(size_t)base * 4 + t];
    __syncthreads();

    float4 w4  = *(const float4*)(ew + t * 4);
    float  ebv = eb[t];
    int s = base % SEQ;
#pragma unroll 4
    for (int tt = 0; tt < 32; ++tt) {
        float4 f = *(const float4*)&fL[tt * 4];
        float v = ebv + f.x * w4.x + f.y * w4.y + f.z * w4.z + f.w * w4.w
                + pe[s * EMB + t];
        hb[(size_t)(base + tt) * EMB + t] = f2b(v);
        if (++s == SEQ) s = 0;
    }
}

// ------------------------------------------------------------------
// bf16 MFMA GEMM (qkv): C = A @ W^T + bias, bf16 out. 128x128, BK=64.
// 512 threads / 8 waves, wave = 64 rows x 32 cols (R16 win).
// XOR-swizzled LDS (R12). Cols < qcols scaled by qscale in epilogue.
// ------------------------------------------------------------------
__global__ __launch_bounds__(512) void bgemm_kernel(
    const unsigned short* __restrict__ A, const unsigned short* __restrict__ W,
    const float* __restrict__ bias, unsigned short* __restrict__ Cb,
    int M, int N, int K, int qcols, float qscale)
{
    __shared__ unsigned short As[128 * 64];   // 16 KB
    __shared__ unsigned short Bs[128 * 64];   // 16 KB

    int t = threadIdx.x;
    int w = t >> 6, l = t & 63;               // w: 0..7
    int quad = l >> 4, lane16 = l & 15;
    int m0 = blockIdx.y * 128, n0 = blockIdx.x * 128;
    int mq = (w >> 2) * 64;                   // row half
    int nq = (w & 3) * 32;                    // col quarter

    int lr8  = l >> 3;
    int scol = ((l & 7) ^ lr8) * 8;           // swizzled global column chunk
    int srow = w * 16 + lr8;                  // wave stages 16 rows
    const unsigned short* Abase = A + (size_t)(m0 + srow) * K + scol;
    const unsigned short* Wbase = W + (size_t)(n0 + srow) * K + scol;
    unsigned short* AsW = As + w * 16 * 64;
    unsigned short* BsW = Bs + w * 16 * 64;

    floatx4 acc[4][2];
#pragma unroll
    for (int i = 0; i < 4; ++i)
#pragma unroll
        for (int j = 0; j < 2; ++j) acc[i][j] = (floatx4){0.f, 0.f, 0.f, 0.f};

    int key = lane16 & 7;

    for (int k0 = 0; k0 < K; k0 += 64) {
        __syncthreads();
#pragma unroll
        for (int c = 0; c < 2; ++c) {         // +c*8 rows keeps row&7 = lr8
            gl_lds16(Abase + (size_t)c * 8 * K + k0, AsW + c * 512);
            gl_lds16(Wbase + (size_t)c * 8 * K + k0, BsW + c * 512);
        }
        __syncthreads();

#pragma unroll
        for (int kk = 0; kk < 2; ++kk) {
            int ch = ((kk * 4 + quad) ^ key) * 8;
            short8 af[4], bf[2];
#pragma unroll
            for (int i = 0; i < 4; ++i)
                af[i] = *(const short8*)&As[(mq + i * 16 + lane16) * 64 + ch];
#pragma unroll
            for (int j = 0; j < 2; ++j)
                bf[j] = *(const short8*)&Bs[(nq + j * 16 + lane16) * 64 + ch];
#pragma unroll
            for (int i = 0; i < 4; ++i)
#pragma unroll
                for (int j = 0; j < 2; ++j)
                    acc[i][j] = __builtin_amdgcn_mfma_f32_16x16x32_bf16(
                                    af[i], bf[j], acc[i][j], 0, 0, 0);
        }
    }

#pragma unroll
    for (int j = 0; j < 2; ++j) {
        int col = n0 + nq + j * 16 + lane16;
        float bb  = bias[col];
        float mul = (col < qcols) ? qscale : 1.0f;
#pragma unroll
        for (int i = 0; i < 4; ++i) {
#pragma unroll
            for (int r = 0; r < 4; ++r) {
                int row = m0 + mq + i * 16 + quad * 4 + r;
                Cb[(size_t)row * N + col] = f2b((acc[i][j][r] + bb) * mul);
            }
        }
    }
}

// ------------------------------------------------------------------
// Fused GEMM + bias + residual(bf16) + LayerNorm -> bf16 out (+qm).
// 512 threads / 8 waves, each wave 32 rows x 64 cols (R10 win).
// BM=64, BN=256, BK=64, XOR-swizzled LDS (R12).
// NOTE (R6+R17 lesson, FINAL): act-gen fused into this K-loop is
// structurally serialized — keep the FFN act de-fused.
// ------------------------------------------------------------------
__global__ __launch_bounds__(512) void bgemm_ln_kernel(
    const unsigned short* __restrict__ A, const unsigned short* __restrict__ W,
    const float* __restrict__ bias, const float* __restrict__ g,
    const float* __restrict__ beta, const float* __restrict__ theta,
    const unsigned short* __restrict__ Rb, unsigned short* __restrict__ OutB,
    float* __restrict__ qm, int K)
{
    __shared__ unsigned short As[64 * 64];     // 8 KB
    __shared__ unsigned short Bs[256 * 64];    // 32 KB
    __shared__ float redS[64][4], redQ[64][4];
    __shared__ float mrow[64], irow[64];

    int t = threadIdx.x;
    int w = t >> 6, l = t & 63;                // w: 0..7
    int quad = l >> 4, lane16 = l & 15;
    int m0 = blockIdx.x * 64;

    int wq = w >> 2;                           // row half
    int cg = w & 3;                            // col group
    int nq = cg * 64;

    int lr8  = l >> 3;
    int lc8s = ((l & 7) ^ lr8) * 8;            // swizzled global column chunk
    const unsigned short* Abase = A + (size_t)(m0 + w * 8 + lr8) * K + lc8s;
    const unsigned short* Wbase = W + (size_t)(w * 8 + lr8) * K + lc8s;
    unsigned short* AsW = As + w * 8 * 64;
    unsigned short* BsW = Bs + w * 8 * 64;

    floatx4 acc[2][4];
#pragma unroll
    for (int i = 0; i < 2; ++i)
#pragma unroll
        for (int j = 0; j < 4; ++j) acc[i][j] = (floatx4){0.f, 0.f, 0.f, 0.f};

    int key = lane16 & 7;

    for (int k0 = 0; k0 < K; k0 += 64) {
        __syncthreads();
        gl_lds16(Abase + k0, AsW);
#pragma unroll
        for (int c = 0; c < 4; ++c)
            gl_lds16(Wbase + (size_t)c * 64 * K + k0, BsW + c * 64 * 64);
        __syncthreads();

#pragma unroll
        for (int kk = 0; kk < 2; ++kk) {
            int ch = ((kk * 4 + quad) ^ key) * 8;
            short8 af[2], bf[4];
#pragma unroll
            for (int i = 0; i < 2; ++i)
                af[i] = *(const short8*)&As[(wq * 32 + i * 16 + lane16) * 64 + ch];
#pragma unroll
            for (int j = 0; j < 4; ++j)
                bf[j] = *(const short8*)&Bs[(nq + j * 16 + lane16) * 64 + ch];
#pragma unroll
            for (int i = 0; i < 2; ++i)
#pragma unroll
                for (int j = 0; j < 4; ++j)
                    acc[i][j] = __builtin_amdgcn_mfma_f32_16x16x32_bf16(
                                    af[i], bf[j], acc[i][j], 0, 0, 0);
        }
    }

    float bb[4];
#pragma unroll
    for (int j = 0; j < 4; ++j) bb[j] = bias[nq + j * 16 + lane16];

#pragma unroll
    for (int i = 0; i < 2; ++i) {
#pragma unroll
        for (int r = 0; r < 4; ++r) {
            int row = wq * 32 + i * 16 + quad * 4 + r;
            const unsigned short* rp = Rb + (size_t)(m0 + row) * EMB;
            float s1 = 0.f, s2 = 0.f;
#pragma unroll
            for (int j = 0; j < 4; ++j) {
                float v = acc[i][j][r] + bb[j] + b2f(rp[nq + j * 16 + lane16]);
                acc[i][j][r] = v;
                s1 += v;
                s2 += v * v;
            }
#pragma unroll
            for (int off = 8; off >= 1; off >>= 1) {
                s1 += __shfl_xor(s1, off);
                s2 += __shfl_xor(s2, off);
            }
            if (lane16 == 0) { redS[row][cg] = s1; redQ[row][cg] = s2; }
        }
    }
    __syncthreads();

    if (t < 64) {
        float s1 = redS[t][0] + redS[t][1] + redS[t][2] + redS[t][3];
        float s2 = redQ[t][0] + redQ[t][1] + redQ[t][2] + redQ[t][3];
        float mean = s1 * (1.0f / 256.0f);
        float var  = s2 * (1.0f / 256.0f) - mean * mean;
        mrow[t] = mean;
        irow[t] = rsqrtf(var + 1e-5f);
    }
    __syncthreads();

    float gv[4], bv[4];
#pragma unroll
    for (int j = 0; j < 4; ++j) {
        int col = nq + j * 16 + lane16;
        gv[j] = g[col];
        bv[j] = beta[col];
    }

#pragma unroll
    for (int i = 0; i < 2; ++i) {
#pragma unroll
        for (int r = 0; r < 4; ++r) {
            int row  = wq * 32 + i * 16 + quad * 4 + r;
            float mean = mrow[row], inv = irow[row];
            size_t base = (size_t)(m0 + row) * EMB;
#pragma unroll
            for (int j = 0; j < 4; ++j) {
                int col = nq + j * 16 + lane16;
                float y = (acc[i][j][r] - mean) * inv * gv[j] + bv[j];
                OutB[base + col] = f2b(y);
                if (qm && cg == 0 && j == 0 && lane16 < NQB)
                    qm[(size_t)(m0 + row) * NQB + lane16] =
                        __cosf(y) * __cosf(theta[lane16]);
            }
        }
    }
}

// ------------------------------------------------------------------
// FFN activation: 16 rows/block, l1wT slab in 64 VGPRs (R13 win).
// ------------------------------------------------------------------
__global__ __launch_bounds__(256) void act_kernel(
    const float* __restrict__ qm, const float* __restrict__ l1wT,
    const float* __restrict__ l1b, unsigned short* __restrict__ act)
{
    __shared__ float qL[16 * NQB];
    int t  = threadIdx.x;
    int m0 = blockIdx.x * 16;

    if (t < 128) qL[t] = qm[(size_t)m0 * NQB + t];

    int f  = (t & 127) * 8;
    int r0 = (t >> 7) * 8;

    float4 wv0[8], wv1[8];
#pragma unroll
    for (int j = 0; j < 8; ++j) {
        wv0[j] = *(const float4*)(l1wT + (size_t)j * FDIM + f);
        wv1[j] = *(const float4*)(l1wT + (size_t)j * FDIM + f + 4);
    }
    float4 b0 = *(const float4*)(l1b + f);
    float4 b1 = *(const float4*)(l1b + f + 4);
    __syncthreads();

#pragma unroll
    for (int rr = 0; rr < 8; ++rr) {
        int row = r0 + rr;
        const float* q = &qL[row * NQB];
        float4 a0 = b0, a1 = b1;
#pragma unroll
        for (int j = 0; j < 8; ++j) {
            float qj = q[j];
            a0.x += qj * wv0[j].x; a0.y += qj * wv0[j].y;
            a0.z += qj * wv0[j].z; a0.w += qj * wv0[j].w;
            a1.x += qj * wv1[j].x; a1.y += qj * wv1[j].y;
            a1.z += qj * wv1[j].z; a1.w += qj * wv1[j].w;
        }
        unsigned short o[8];
        o[0] = f2b(fmaxf(a0.x, 0.f)); o[1] = f2b(fmaxf(a0.y, 0.f));
        o[2] = f2b(fmaxf(a0.z, 0.f)); o[3] = f2b(fmaxf(a0.w, 0.f));
        o[4] = f2b(fmaxf(a1.x, 0.f)); o[5] = f2b(fmaxf(a1.y, 0.f));
        o[6] = f2b(fmaxf(a1.z, 0.f)); o[7] = f2b(fmaxf(a1.w, 0.f));
        *(short8*)(act + (size_t)(m0 + row) * FDIM + f) = *(short8*)o;
    }
}

// ------------------------------------------------------------------
// MFMA flash attention. R21: all Q fragments (<=4) prefetched BEFORE
// the qt loop + full unroll — the per-iteration strided af load was
// a serial ~200-900cyc stall in front of the 13 QK MFMAs (R20
// counters: all pipes <35%, latency-bound). Prefetching batches the
// 4 loads with the kf/vb preamble and lets the compiler interleave
// iteration i's softmax/PV with iteration i+1's QK MFMAs.
// Keeps: HW exp2/rcp (R20), MFMA row-sum (R19), register V/K
// (R18/R11), no-max exp2 (R16), Ps stride 232 (R15), no barriers.
// ------------------------------------------------------------------
__global__ __launch_bounds__(256, 3) void attn_kernel(
    const unsigned short* __restrict__ qkv, unsigned short* __restrict__ ob)
{
    __shared__ unsigned short Ps[64 * 232];    // 29 KB, 16 rows per wave

    int t  = threadIdx.x;
    int bh = blockIdx.x;
    int b  = bh >> 3;
    int hh = bh & 7;
    const unsigned short* base = qkv + (size_t)b * SEQ * 768 + hh * HDIM;

    int w = t >> 6, l = t & 63;
    int quad = l >> 4, lane16 = l & 15;
    unsigned short* Pw = Ps + w * 16 * 232;

    // zero own-wave Ps pad cols 208..231 (per-wave region, no barrier)
    for (int idx = l; idx < 16 * 24; idx += 64) {
        int r = idx / 24, c = 208 + idx % 24;
        Pw[r * 232 + c] = 0;
    }

    // Q fragments for this wave's (<=4) qt tiles, prefetched upfront.
    short8 afv[4];
#pragma unroll
    for (int it = 0; it < 4; ++it) {
        int qt = w + it * 4;
        if (qt < 13)
            afv[it] = *(const short8*)(base + (size_t)(qt * 16 + lane16) * 768 + quad * 8);
    }

    // K fragments: qt-invariant, 13 x short8 (52 VGPRs)
    short8 kf[13];
#pragma unroll
    for (int kt = 0; kt < 13; ++kt)
        kf[kt] = *(const short8*)(base + (size_t)(kt * 16 + lane16) * 768 + 256 + quad * 8);

    // V fragments: qt-invariant, 14 x short8, s>=SEQ zeroed (c=6 only).
    short8 vb[2][7];
#pragma unroll
    for (int nt = 0; nt < 2; ++nt) {
#pragma unroll
        for (int c = 0; c < 7; ++c) {
            unsigned short tmp[8];
#pragma unroll
            for (int j = 0; j < 8; ++j) {
                int s = c * 32 + quad * 8 + j;
                tmp[j] = (s < SEQ)
                    ? base[(size_t)s * 768 + 512 + nt * 16 + lane16]
                    : (unsigned short)0;
            }
            vb[nt][c] = *(short8*)tmp;
        }
    }

    // ones-column B-tile: n=lane16==0 col is 1.0bf16 for valid s.
    short8 vone[7];
#pragma unroll
    for (int c = 0; c < 7; ++c) {
        unsigned short tmp[8];
#pragma unroll
        for (int j = 0; j < 8; ++j) {
            int s = c * 32 + quad * 8 + j;
            tmp[j] = (lane16 == 0 && s < SEQ) ? (unsigned short)0x3F80 : (unsigned short)0;
        }
        vone[c] = *(short8*)tmp;
    }

#pragma unroll
    for (int it = 0; it < 4; ++it) {
        int qt = w + it * 4;
        if (qt >= 13) break;
        short8 af = afv[it];

        floatx4 sc[13];
#pragma unroll
        for (int kt = 0; kt < 13; ++kt) {
            floatx4 z = {0.f, 0.f, 0.f, 0.f};
            sc[kt] = __builtin_amdgcn_mfma_f32_16x16x32_bf16(af, kf[kt], z, 0, 0, 0);
        }

        // no max-subtraction; no VALU lsum — single-instr exp2 + store
#pragma unroll
        for (int kt = 0; kt < 13; ++kt) {
#pragma unroll
            for (int r = 0; r < 4; ++r) {
                float v = sc[kt][r];
                if (kt == 12 && lane16 >= 4) v = -1e30f;   // keys 196..207
                Pw[(quad * 4 + r) * 232 + kt * 16 + lane16] =
                    f2b(__builtin_amdgcn_exp2f(v));
            }
        }

        floatx4 oacc[2] = {{0.f,0.f,0.f,0.f},{0.f,0.f,0.f,0.f}};
        floatx4 osum    = {0.f,0.f,0.f,0.f};
#pragma unroll
        for (int c = 0; c < 7; ++c) {
            short8 pa = *(const short8*)&Pw[lane16 * 232 + c * 32 + quad * 8];
#pragma unroll
            for (int nt = 0; nt < 2; ++nt)
                oacc[nt] = __builtin_amdgcn_mfma_f32_16x16x32_bf16(
                               pa, vb[nt][c], oacc[nt], 0, 0, 0);
            osum = __builtin_amdgcn_mfma_f32_16x16x32_bf16(
                       pa, vone[c], osum, 0, 0, 0);
        }

#pragma unroll
        for (int r = 0; r < 4; ++r) {
            int srow = qt * 16 + quad * 4 + r;
            float lsum = __shfl(osum[r], (l & 48));   // row sum lives in lane16==0
            if (srow < SEQ) {
                float invl = __builtin_amdgcn_rcpf(lsum);
                unsigned short* op = ob + ((size_t)b * SEQ + srow) * EMB + hh * HDIM;
                op[lane16]      = f2b(oacc[0][r] * invl);
                op[16 + lane16] = f2b(oacc[1][r] * invl);
            }
        }
    }
}

// ------------------------------------------------------------------
// Mean-pool over S (bf16 stream in) then classifier (fp32).
// ------------------------------------------------------------------
__global__ __launch_bounds__(256) void pool_cls_kernel(
    const unsigned short* __restrict__ hb, const float* __restrict__ cw,
    const float* __restrict__ cb, float* __restrict__ out)
{
    __shared__ float pooled[EMB];
    int b = blockIdx.x;
    int e = threadIdx.x;
    float s = 0.f;
    const unsigned short* hp = hb + (size_t)b * SEQ * EMB + e;
    for (int j = 0; j < SEQ; ++j) s += b2f(hp[(size_t)j * EMB]);
    pooled[e] = s * (1.0f / (float)SEQ);
    __syncthreads();
    if (e < NCLS) {
        float acc = cb[e];
        const float* wr = cw + e * EMB;
        for (int k = 0; k < EMB; ++k) acc += pooled[k] * wr[k];
        out[b * NCLS + e] = acc;
    }
}

// ------------------------------------------------------------------
extern "C" void kernel_launch(void* const* d_in, const int* in_sizes, int n_in,
                              void* d_out, int out_size, void* d_ws, size_t ws_size,
                              hipStream_t stream)
{
    const float* x         = (const float*)d_in[0];
    const float* qfilter_w = (const float*)d_in[1];
    const float* qfilter_b = (const float*)d_in[2];
    const float* pw_w      = (const float*)d_in[3];
    const float* pw_b      = (const float*)d_in[4];
    const float* embed_w   = (const float*)d_in[5];
    const float* embed_b   = (const float*)d_in[6];
    const float* in_proj_w = (const float*)d_in[7];
    const float* in_proj_b = (const float*)d_in[8];
    const float* out_w     = (const float*)d_in[9];
    const float* out_b     = (const float*)d_in[10];
    const float* theta     = (const float*)d_in[11];
    const float* l1_w      = (const float*)d_in[12];
    const float* l1_b      = (const float*)d_in[13];
    const float* l2_w      = (const float*)d_in[14];
    const float* l2_b      = (const float*)d_in[15];
    const float* ln1_g     = (const float*)d_in[16];
    const float* ln1_b     = (const float*)d_in[17];
    const float* ln2_g     = (const float*)d_in[18];
    const float* ln2_b     = (const float*)d_in[19];
    const float* cls_w     = (const float*)d_in[20];
    const float* cls_b     = (const float*)d_in[21];

    char* ws = (char*)d_ws;
    // big region time-shared: qkv bf16 [M,768] (77MB) then act bf16 [M,1024] (103MB)
    unsigned short* big = (unsigned short*)ws; ws += (size_t)MROWS * FDIM * 2;  // 102.8MB
    float* qm  = (float*)ws;                   ws += (size_t)MROWS * NQB * 4;   // 1.6MB
    float* pe  = (float*)ws;                   ws += (size_t)SEQ * EMB * 4;
    float* feat = (float*)ws;                  ws += (size_t)MROWS * 4 * 4;     // 0.8MB
    unsigned short* hb  = (unsigned short*)ws; ws += (size_t)MROWS * EMB * 2;   // 25.7MB  (post-LN2 / embed stream)
    unsigned short* hb1 = (unsigned short*)ws; ws += (size_t)MROWS * EMB * 2;   // 25.7MB  (post-LN1 stream)
    unsigned short* ob  = (unsigned short*)ws; ws += (size_t)MROWS * EMB * 2;   // 25.7MB
    unsigned short* wb_in = (unsigned short*)ws; ws += (size_t)NBLK * 768 * EMB * 2;
    unsigned short* wb_o  = (unsigned short*)ws; ws += (size_t)NBLK * EMB * EMB * 2;
    unsigned short* wb_l2 = (unsigned short*)ws; ws += (size_t)NBLK * EMB * FDIM * 2;
    float* l1wT = (float*)ws;                  ws += (size_t)NBLK * NQB * FDIM * 4;

    unsigned short* qkvb = big;
    unsigned short* act  = big;

    pe_kernel<<<SEQ, EMB, 0, stream>>>(pe);
    {
        int n1 = NBLK * 768 * EMB;
        int n2 = NBLK * EMB * EMB;
        int n3 = NBLK * EMB * FDIM;
        cvt_kernel<<<n1 / 1024, 256, 0, stream>>>(in_proj_w, wb_in, n1);
        cvt_kernel<<<n2 / 1024, 256, 0, stream>>>(out_w,     wb_o,  n2);
        cvt_kernel<<<n3 / 1024, 256, 0, stream>>>(l2_w,      wb_l2, n3);
        l1t_kernel<<<(NBLK * FDIM * NQB) / 256, 256, 0, stream>>>(l1_w, l1wT);
    }

    feat_kernel<<<(MROWS * 4) / 256, 256, 0, stream>>>(
        x, qfilter_w, qfilter_b, pw_w, pw_b, feat);
    embed2_kernel<<<MROWS / 32, 256, 0, stream>>>(
        feat, embed_w, embed_b, pe, hb);

    for (int i = 0; i < NBLK; ++i) {
        // QKV projection -> bf16 [M,768]; Q cols pre-scaled for exp2 softmax
        bgemm_kernel<<<dim3(6, MROWS / 128), 512, 0, stream>>>(
            hb, wb_in + (size_t)i * 768 * EMB, in_proj_b + i * 768,
            qkvb, MROWS, 768, EMB, 256, QSCALE);
        // MFMA flash attention (bf16 in/out), Q-prefetch + register V/K
        attn_kernel<<<BATCH * HEADS, 256, 0, stream>>>(qkvb, ob);
        // out-proj + residual(hb) + LN1 -> hb1 (+qm)
        bgemm_ln_kernel<<<MROWS / 64, 512, 0, stream>>>(
            ob, wb_o + (size_t)i * EMB * EMB, out_b + i * EMB,
            ln1_g + i * EMB, ln1_b + i * EMB, theta + i * NQB,
            hb, hb1, qm, EMB);
        // FFN activation (16 rows/block, weights in registers); act overwrites qkv
        act_kernel<<<MROWS / 16, 256, 0, stream>>>(
            qm, l1wT + (size_t)i * NQB * FDIM, l1_b + i * FDIM, act);
        // FFN l2 + residual(hb1) + LN2 -> hb (next layer's stream)
        bgemm_ln_kernel<<<MROWS / 64, 512, 0, stream>>>(
            act, wb_l2 + (size_t)i * EMB * FDIM, l2_b + i * EMB,
            ln2_g + i * EMB, ln2_b + i * EMB, nullptr,
            hb1, hb, nullptr, FDIM);
    }

    pool_cls_kernel<<<BATCH, EMB, 0, stream>>>(hb, cls_w, cls_b, (float*)d_out);
}

// Round 22
// 905.404 us; speedup vs baseline: 1.1967x; 1.1967x over previous
//
#include <hip/hip_runtime.h>
#include <math.h>

#define BATCH 256
#define SEQ   196
#define EMB   256
#define HEADS 8
#define HDIM  32
#define NBLK  4
#define FDIM  1024
#define NQB   8
#define NCLS  10
#define MROWS (BATCH*SEQ)   // 50176 = 392*128 = 784*64 = 3136*16

typedef __attribute__((ext_vector_type(8))) short  short8;   // 8 bf16 (4 VGPRs)
typedef __attribute__((ext_vector_type(4))) float  floatx4;  // MFMA acc

// fp32 -> bf16 RNE
__device__ __forceinline__ unsigned short f2b(float f) {
    unsigned u = __builtin_bit_cast(unsigned, f);
    u += 0x7fffu + ((u >> 16) & 1u);
    return (unsigned short)(u >> 16);
}
// bf16 -> fp32
__device__ __forceinline__ float b2f(unsigned short u) {
    return __builtin_bit_cast(float, ((unsigned)u) << 16);
}

// async global->LDS, 16B per lane. LDS dest is wave-uniform base; HW adds lane*16.
__device__ __forceinline__ void gl_lds16(const void* g, void* l) {
    __builtin_amdgcn_global_load_lds(
        (const __attribute__((address_space(1))) unsigned int*)g,
        (__attribute__((address_space(3))) unsigned int*)l, 16, 0, 0);
}

// softmax scale (1/sqrt(32)) * log2(e): Q pre-scaled so scores exit the
// QK MFMA in exp2 domain.
#define QSCALE (0.17677669529663687f * 1.4426950408889634f)

// ------------------------------------------------------------------
// Positional encoding table
// ------------------------------------------------------------------
__global__ void pe_kernel(float* __restrict__ pe) {
    int s = blockIdx.x, e = threadIdx.x;
    int j2 = (e >> 1) * 2;
    float dv  = expf(-(float)j2 * (logf(10000.0f) / (float)EMB));
    float ang = (float)s * dv;
    pe[s * EMB + e] = (e & 1) ? cosf(ang) : sinf(ang);
}

// ------------------------------------------------------------------
// fp32 -> bf16 bulk convert (weights), n % 4 == 0
// ------------------------------------------------------------------
__global__ __launch_bounds__(256) void cvt_kernel(
    const float* __restrict__ src, unsigned short* __restrict__ dst, int n)
{
    int i = (blockIdx.x * 256 + threadIdx.x) * 4;
    if (i < n) {
        float4 v = *(const float4*)(src + i);
        ushort4 o;
        o.x = f2b(v.x); o.y = f2b(v.y); o.z = f2b(v.z); o.w = f2b(v.w);
        *(ushort4*)(dst + i) = o;
    }
}

// ------------------------------------------------------------------
// l1_w [NBLK][FDIM][NQB] -> l1wT [NBLK][NQB][FDIM]  (fp32)
// ------------------------------------------------------------------
__global__ __launch_bounds__(256) void l1t_kernel(
    const float* __restrict__ src, float* __restrict__ dst)
{
    int idx = blockIdx.x * 256 + threadIdx.x;   // (i*FDIM + f)*NQB + q
    int i = idx >> 13, rem = idx & 8191;
    int q = rem & 7, f = rem >> 3;
    dst[((size_t)i * NQB + q) * FDIM + f] = src[idx];
}

// ------------------------------------------------------------------
// Stage 1: conv features, one thread per (token, c). feat[MROWS][4].
// ------------------------------------------------------------------
__global__ __launch_bounds__(256) void feat_kernel(
    const float* __restrict__ x,  const float* __restrict__ qw,
    const float* __restrict__ qb, const float* __restrict__ pw,
    const float* __restrict__ pb, float* __restrict__ feat)
{
    int idx = blockIdx.x * 256 + threadIdx.x;   // < MROWS*4
    int bs = idx >> 2, c = idx & 3;
    int b  = bs / SEQ, s = bs % SEQ;
    int co = s / 49;
    int p  = (s % 49) * 4 + c;
    int hh = p / 14, ww = p % 14;

    float dw[4];
#pragma unroll
    for (int ci = 0; ci < 4; ++ci) {
        const float* xp = x + (((size_t)b * 4 + ci) * 28 + hh * 2) * 28 + ww * 2;
        dw[ci] = qb[ci] + xp[0]  * qw[ci * 4 + 0] + xp[1]  * qw[ci * 4 + 1]
                        + xp[28] * qw[ci * 4 + 2] + xp[29] * qw[ci * 4 + 3];
    }
    feat[idx] = pb[co] + pw[co * 4 + 0] * dw[0] + pw[co * 4 + 1] * dw[1]
                       + pw[co * 4 + 2] * dw[2] + pw[co * 4 + 3] * dw[3];
}

// ------------------------------------------------------------------
// Stage 2: embed + PE -> hb (bf16 stream)
// ------------------------------------------------------------------
__global__ __launch_bounds__(256) void embed2_kernel(
    const float* __restrict__ feat, const float* __restrict__ ew,
    const float* __restrict__ eb,   const float* __restrict__ pe,
    unsigned short* __restrict__ hb)
{
    __shared__ float fL[32 * 4];
    int t = threadIdx.x;
    int base = blockIdx.x * 32;

    if (t < 128) fL[t] = feat[(size_t)base * 4 + t];
    __syncthreads();

    float4 w4  = *(const float4*)(ew + t * 4);
    float  ebv = eb[t];
    int s = base % SEQ;
#pragma unroll 4
    for (int tt = 0; tt < 32; ++tt) {
        float4 f = *(const float4*)&fL[tt * 4];
        float v = ebv + f.x * w4.x + f.y * w4.y + f.z * w4.z + f.w * w4.w
                + pe[s * EMB + t];
        hb[(size_t)(base + tt) * EMB + t] = f2b(v);
        if (++s == SEQ) s = 0;
    }
}

// ------------------------------------------------------------------
// bf16 MFMA GEMM (qkv): C = A @ W^T + bias, bf16 out. 128x128, BK=64.
// 512 threads / 8 waves, wave = 64 rows x 32 cols (R16 win).
// XOR-swizzled LDS (R12). Cols < qcols scaled by qscale in epilogue.
// ------------------------------------------------------------------
__global__ __launch_bounds__(512) void bgemm_kernel(
    const unsigned short* __restrict__ A, const unsigned short* __restrict__ W,
    const float* __restrict__ bias, unsigned short* __restrict__ Cb,
    int M, int N, int K, int qcols, float qscale)
{
    __shared__ unsigned short As[128 * 64];   // 16 KB
    __shared__ unsigned short Bs[128 * 64];   // 16 KB

    int t = threadIdx.x;
    int w = t >> 6, l = t & 63;               // w: 0..7
    int quad = l >> 4, lane16 = l & 15;
    int m0 = blockIdx.y * 128, n0 = blockIdx.x * 128;
    int mq = (w >> 2) * 64;                   // row half
    int nq = (w & 3) * 32;                    // col quarter

    int lr8  = l >> 3;
    int scol = ((l & 7) ^ lr8) * 8;           // swizzled global column chunk
    int srow = w * 16 + lr8;                  // wave stages 16 rows
    const unsigned short* Abase = A + (size_t)(m0 + srow) * K + scol;
    const unsigned short* Wbase = W + (size_t)(n0 + srow) * K + scol;
    unsigned short* AsW = As + w * 16 * 64;
    unsigned short* BsW = Bs + w * 16 * 64;

    floatx4 acc[4][2];
#pragma unroll
    for (int i = 0; i < 4; ++i)
#pragma unroll
        for (int j = 0; j < 2; ++j) acc[i][j] = (floatx4){0.f, 0.f, 0.f, 0.f};

    int key = lane16 & 7;

    for (int k0 = 0; k0 < K; k0 += 64) {
        __syncthreads();
#pragma unroll
        for (int c = 0; c < 2; ++c) {         // +c*8 rows keeps row&7 = lr8
            gl_lds16(Abase + (size_t)c * 8 * K + k0, AsW + c * 512);
            gl_lds16(Wbase + (size_t)c * 8 * K + k0, BsW + c * 512);
        }
        __syncthreads();

#pragma unroll
        for (int kk = 0; kk < 2; ++kk) {
            int ch = ((kk * 4 + quad) ^ key) * 8;
            short8 af[4], bf[2];
#pragma unroll
            for (int i = 0; i < 4; ++i)
                af[i] = *(const short8*)&As[(mq + i * 16 + lane16) * 64 + ch];
#pragma unroll
            for (int j = 0; j < 2; ++j)
                bf[j] = *(const short8*)&Bs[(nq + j * 16 + lane16) * 64 + ch];
#pragma unroll
            for (int i = 0; i < 4; ++i)
#pragma unroll
                for (int j = 0; j < 2; ++j)
                    acc[i][j] = __builtin_amdgcn_mfma_f32_16x16x32_bf16(
                                    af[i], bf[j], acc[i][j], 0, 0, 0);
        }
    }

#pragma unroll
    for (int j = 0; j < 2; ++j) {
        int col = n0 + nq + j * 16 + lane16;
        float bb  = bias[col];
        float mul = (col < qcols) ? qscale : 1.0f;
#pragma unroll
        for (int i = 0; i < 4; ++i) {
#pragma unroll
            for (int r = 0; r < 4; ++r) {
                int row = m0 + mq + i * 16 + quad * 4 + r;
                Cb[(size_t)row * N + col] = f2b((acc[i][j][r] + bb) * mul);
            }
        }
    }
}

// ------------------------------------------------------------------
// Fused GEMM + bias + residual(bf16) + LayerNorm -> bf16 out (+qm).
// 512 threads / 8 waves, each wave 32 rows x 64 cols (R10 win).
// BM=64, BN=256, BK=64, XOR-swizzled LDS (R12).
// NOTE (R6+R17 lesson, FINAL): act-gen fused into this K-loop is
// structurally serialized — keep the FFN act de-fused.
// ------------------------------------------------------------------
__global__ __launch_bounds__(512) void bgemm_ln_kernel(
    const unsigned short* __restrict__ A, const unsigned short* __restrict__ W,
    const float* __restrict__ bias, const float* __restrict__ g,
    const float* __restrict__ beta, const float* __restrict__ theta,
    const unsigned short* __restrict__ Rb, unsigned short* __restrict__ OutB,
    float* __restrict__ qm, int K)
{
    __shared__ unsigned short As[64 * 64];     // 8 KB
    __shared__ unsigned short Bs[256 * 64];    // 32 KB
    __shared__ float redS[64][4], redQ[64][4];
    __shared__ float mrow[64], irow[64];

    int t = threadIdx.x;
    int w = t >> 6, l = t & 63;                // w: 0..7
    int quad = l >> 4, lane16 = l & 15;
    int m0 = blockIdx.x * 64;

    int wq = w >> 2;                           // row half
    int cg = w & 3;                            // col group
    int nq = cg * 64;

    int lr8  = l >> 3;
    int lc8s = ((l & 7) ^ lr8) * 8;            // swizzled global column chunk
    const unsigned short* Abase = A + (size_t)(m0 + w * 8 + lr8) * K + lc8s;
    const unsigned short* Wbase = W + (size_t)(w * 8 + lr8) * K + lc8s;
    unsigned short* AsW = As + w * 8 * 64;
    unsigned short* BsW = Bs + w * 8 * 64;

    floatx4 acc[2][4];
#pragma unroll
    for (int i = 0; i < 2; ++i)
#pragma unroll
        for (int j = 0; j < 4; ++j) acc[i][j] = (floatx4){0.f, 0.f, 0.f, 0.f};

    int key = lane16 & 7;

    for (int k0 = 0; k0 < K; k0 += 64) {
        __syncthreads();
        gl_lds16(Abase + k0, AsW);
#pragma unroll
        for (int c = 0; c < 4; ++c)
            gl_lds16(Wbase + (size_t)c * 64 * K + k0, BsW + c * 64 * 64);
        __syncthreads();

#pragma unroll
        for (int kk = 0; kk < 2; ++kk) {
            int ch = ((kk * 4 + quad) ^ key) * 8;
            short8 af[2], bf[4];
#pragma unroll
            for (int i = 0; i < 2; ++i)
                af[i] = *(const short8*)&As[(wq * 32 + i * 16 + lane16) * 64 + ch];
#pragma unroll
            for (int j = 0; j < 4; ++j)
                bf[j] = *(const short8*)&Bs[(nq + j * 16 + lane16) * 64 + ch];
#pragma unroll
            for (int i = 0; i < 2; ++i)
#pragma unroll
                for (int j = 0; j < 4; ++j)
                    acc[i][j] = __builtin_amdgcn_mfma_f32_16x16x32_bf16(
                                    af[i], bf[j], acc[i][j], 0, 0, 0);
        }
    }

    float bb[4];
#pragma unroll
    for (int j = 0; j < 4; ++j) bb[j] = bias[nq + j * 16 + lane16];

#pragma unroll
    for (int i = 0; i < 2; ++i) {
#pragma unroll
        for (int r = 0; r < 4; ++r) {
            int row = wq * 32 + i * 16 + quad * 4 + r;
            const unsigned short* rp = Rb + (size_t)(m0 + row) * EMB;
            float s1 = 0.f, s2 = 0.f;
#pragma unroll
            for (int j = 0; j < 4; ++j) {
                float v = acc[i][j][r] + bb[j] + b2f(rp[nq + j * 16 + lane16]);
                acc[i][j][r] = v;
                s1 += v;
                s2 += v * v;
            }
#pragma unroll
            for (int off = 8; off >= 1; off >>= 1) {
                s1 += __shfl_xor(s1, off);
                s2 += __shfl_xor(s2, off);
            }
            if (lane16 == 0) { redS[row][cg] = s1; redQ[row][cg] = s2; }
        }
    }
    __syncthreads();

    if (t < 64) {
        float s1 = redS[t][0] + redS[t][1] + redS[t][2] + redS[t][3];
        float s2 = redQ[t][0] + redQ[t][1] + redQ[t][2] + redQ[t][3];
        float mean = s1 * (1.0f / 256.0f);
        float var  = s2 * (1.0f / 256.0f) - mean * mean;
        mrow[t] = mean;
        irow[t] = rsqrtf(var + 1e-5f);
    }
    __syncthreads();

    float gv[4], bv[4];
#pragma unroll
    for (int j = 0; j < 4; ++j) {
        int col = nq + j * 16 + lane16;
        gv[j] = g[col];
        bv[j] = beta[col];
    }

#pragma unroll
    for (int i = 0; i < 2; ++i) {
#pragma unroll
        for (int r = 0; r < 4; ++r) {
            int row  = wq * 32 + i * 16 + quad * 4 + r;
            float mean = mrow[row], inv = irow[row];
            size_t base = (size_t)(m0 + row) * EMB;
#pragma unroll
            for (int j = 0; j < 4; ++j) {
                int col = nq + j * 16 + lane16;
                float y = (acc[i][j][r] - mean) * inv * gv[j] + bv[j];
                OutB[base + col] = f2b(y);
                if (qm && cg == 0 && j == 0 && lane16 < NQB)
                    qm[(size_t)(m0 + row) * NQB + lane16] =
                        __cosf(y) * __cosf(theta[lane16]);
            }
        }
    }
}

// ------------------------------------------------------------------
// FFN activation: 16 rows/block, l1wT slab in 64 VGPRs (R13 win).
// ------------------------------------------------------------------
__global__ __launch_bounds__(256) void act_kernel(
    const float* __restrict__ qm, const float* __restrict__ l1wT,
    const float* __restrict__ l1b, unsigned short* __restrict__ act)
{
    __shared__ float qL[16 * NQB];
    int t  = threadIdx.x;
    int m0 = blockIdx.x * 16;

    if (t < 128) qL[t] = qm[(size_t)m0 * NQB + t];

    int f  = (t & 127) * 8;
    int r0 = (t >> 7) * 8;

    float4 wv0[8], wv1[8];
#pragma unroll
    for (int j = 0; j < 8; ++j) {
        wv0[j] = *(const float4*)(l1wT + (size_t)j * FDIM + f);
        wv1[j] = *(const float4*)(l1wT + (size_t)j * FDIM + f + 4);
    }
    float4 b0 = *(const float4*)(l1b + f);
    float4 b1 = *(const float4*)(l1b + f + 4);
    __syncthreads();

#pragma unroll
    for (int rr = 0; rr < 8; ++rr) {
        int row = r0 + rr;
        const float* q = &qL[row * NQB];
        float4 a0 = b0, a1 = b1;
#pragma unroll
        for (int j = 0; j < 8; ++j) {
            float qj = q[j];
            a0.x += qj * wv0[j].x; a0.y += qj * wv0[j].y;
            a0.z += qj * wv0[j].z; a0.w += qj * wv0[j].w;
            a1.x += qj * wv1[j].x; a1.y += qj * wv1[j].y;
            a1.z += qj * wv1[j].z; a1.w += qj * wv1[j].w;
        }
        unsigned short o[8];
        o[0] = f2b(fmaxf(a0.x, 0.f)); o[1] = f2b(fmaxf(a0.y, 0.f));
        o[2] = f2b(fmaxf(a0.z, 0.f)); o[3] = f2b(fmaxf(a0.w, 0.f));
        o[4] = f2b(fmaxf(a1.x, 0.f)); o[5] = f2b(fmaxf(a1.y, 0.f));
        o[6] = f2b(fmaxf(a1.z, 0.f)); o[7] = f2b(fmaxf(a1.w, 0.f));
        *(short8*)(act + (size_t)(m0 + row) * FDIM + f) = *(short8*)o;
    }
}

// ------------------------------------------------------------------
// MFMA flash attention — R20 configuration (measured 55us, best).
// Rolled qt loop with per-iteration af load. R21 lesson: with ~122
// VGPRs of qt-invariant operands (kf/vb/vone) resident, prefetching
// Q + unrolling spills to scratch (WRITE_SIZE 43->161MB) — keep the
// loop rolled. HW exp2/rcp (R20), MFMA row-sum (R19), register V/K
// (R18/R11), no-max exp2 (R16), Ps stride 232 (R15), no barriers.
// ------------------------------------------------------------------
__global__ __launch_bounds__(256, 3) void attn_kernel(
    const unsigned short* __restrict__ qkv, unsigned short* __restrict__ ob)
{
    __shared__ unsigned short Ps[64 * 232];    // 29 KB, 16 rows per wave

    int t  = threadIdx.x;
    int bh = blockIdx.x;
    int b  = bh >> 3;
    int hh = bh & 7;
    const unsigned short* base = qkv + (size_t)b * SEQ * 768 + hh * HDIM;

    int w = t >> 6, l = t & 63;
    int quad = l >> 4, lane16 = l & 15;
    unsigned short* Pw = Ps + w * 16 * 232;

    // zero own-wave Ps pad cols 208..231 (per-wave region, no barrier)
    for (int idx = l; idx < 16 * 24; idx += 64) {
        int r = idx / 24, c = 208 + idx % 24;
        Pw[r * 232 + c] = 0;
    }

    // K fragments: qt-invariant, 13 x short8 (52 VGPRs)
    short8 kf[13];
#pragma unroll
    for (int kt = 0; kt < 13; ++kt)
        kf[kt] = *(const short8*)(base + (size_t)(kt * 16 + lane16) * 768 + 256 + quad * 8);

    // V fragments: qt-invariant, 14 x short8, s>=SEQ zeroed (c=6 only).
    short8 vb[2][7];
#pragma unroll
    for (int nt = 0; nt < 2; ++nt) {
#pragma unroll
        for (int c = 0; c < 7; ++c) {
            unsigned short tmp[8];
#pragma unroll
            for (int j = 0; j < 8; ++j) {
                int s = c * 32 + quad * 8 + j;
                tmp[j] = (s < SEQ)
                    ? base[(size_t)s * 768 + 512 + nt * 16 + lane16]
                    : (unsigned short)0;
            }
            vb[nt][c] = *(short8*)tmp;
        }
    }

    // ones-column B-tile: n=lane16==0 col is 1.0bf16 for valid s.
    short8 vone[7];
#pragma unroll
    for (int c = 0; c < 7; ++c) {
        unsigned short tmp[8];
#pragma unroll
        for (int j = 0; j < 8; ++j) {
            int s = c * 32 + quad * 8 + j;
            tmp[j] = (lane16 == 0 && s < SEQ) ? (unsigned short)0x3F80 : (unsigned short)0;
        }
        vone[c] = *(short8*)tmp;
    }

    for (int qt = w; qt < 13; qt += 4) {
        short8 af = *(const short8*)(base + (size_t)(qt * 16 + lane16) * 768 + quad * 8);

        floatx4 sc[13];
#pragma unroll
        for (int kt = 0; kt < 13; ++kt) {
            floatx4 z = {0.f, 0.f, 0.f, 0.f};
            sc[kt] = __builtin_amdgcn_mfma_f32_16x16x32_bf16(af, kf[kt], z, 0, 0, 0);
        }

        // no max-subtraction; no VALU lsum — single-instr exp2 + store
#pragma unroll
        for (int kt = 0; kt < 13; ++kt) {
#pragma unroll
            for (int r = 0; r < 4; ++r) {
                float v = sc[kt][r];
                if (kt == 12 && lane16 >= 4) v = -1e30f;   // keys 196..207
                Pw[(quad * 4 + r) * 232 + kt * 16 + lane16] =
                    f2b(__builtin_amdgcn_exp2f(v));
            }
        }

        floatx4 oacc[2] = {{0.f,0.f,0.f,0.f},{0.f,0.f,0.f,0.f}};
        floatx4 osum    = {0.f,0.f,0.f,0.f};
#pragma unroll
        for (int c = 0; c < 7; ++c) {
            short8 pa = *(const short8*)&Pw[lane16 * 232 + c * 32 + quad * 8];
#pragma unroll
            for (int nt = 0; nt < 2; ++nt)
                oacc[nt] = __builtin_amdgcn_mfma_f32_16x16x32_bf16(
                               pa, vb[nt][c], oacc[nt], 0, 0, 0);
            osum = __builtin_amdgcn_mfma_f32_16x16x32_bf16(
                       pa, vone[c], osum, 0, 0, 0);
        }

#pragma unroll
        for (int r = 0; r < 4; ++r) {
            int srow = qt * 16 + quad * 4 + r;
            float lsum = __shfl(osum[r], (l & 48));   // row sum lives in lane16==0
            if (srow < SEQ) {
                float invl = __builtin_amdgcn_rcpf(lsum);
                unsigned short* op = ob + ((size_t)b * SEQ + srow) * EMB + hh * HDIM;
                op[lane16]      = f2b(oacc[0][r] * invl);
                op[16 + lane16] = f2b(oacc[1][r] * invl);
            }
        }
    }
}

// ------------------------------------------------------------------
// Mean-pool over S (bf16 stream in) then classifier (fp32).
// ------------------------------------------------------------------
__global__ __launch_bounds__(256) void pool_cls_kernel(
    const unsigned short* __restrict__ hb, const float* __restrict__ cw,
    const float* __restrict__ cb, float* __restrict__ out)
{
    __shared__ float pooled[EMB];
    int b = blockIdx.x;
    int e = threadIdx.x;
    float s = 0.f;
    const unsigned short* hp = hb + (size_t)b * SEQ * EMB + e;
    for (int j = 0; j < SEQ; ++j) s += b2f(hp[(size_t)j * EMB]);
    pooled[e] = s * (1.0f / (float)SEQ);
    __syncthreads();
    if (e < NCLS) {
        float acc = cb[e];
        const float* wr = cw + e * EMB;
        for (int k = 0; k < EMB; ++k) acc += pooled[k] * wr[k];
        out[b * NCLS + e] = acc;
    }
}

// ------------------------------------------------------------------
extern "C" void kernel_launch(void* const* d_in, const int* in_sizes, int n_in,
                              void* d_out, int out_size, void* d_ws, size_t ws_size,
                              hipStream_t stream)
{
    const float* x         = (const float*)d_in[0];
    const float* qfilter_w = (const float*)d_in[1];
    const float* qfilter_b = (const float*)d_in[2];
    const float* pw_w      = (const float*)d_in[3];
    const float* pw_b      = (const float*)d_in[4];
    const float* embed_w   = (const float*)d_in[5];
    const float* embed_b   = (const float*)d_in[6];
    const float* in_proj_w = (const float*)d_in[7];
    const float* in_proj_b = (const float*)d_in[8];
    const float* out_w     = (const float*)d_in[9];
    const float* out_b     = (const float*)d_in[10];
    const float* theta     = (const float*)d_in[11];
    const float* l1_w      = (const float*)d_in[12];
    const float* l1_b      = (const float*)d_in[13];
    const float* l2_w      = (const float*)d_in[14];
    const float* l2_b      = (const float*)d_in[15];
    const float* ln1_g     = (const float*)d_in[16];
    const float* ln1_b     = (const float*)d_in[17];
    const float* ln2_g     = (const float*)d_in[18];
    const float* ln2_b     = (const float*)d_in[19];
    const float* cls_w     = (const float*)d_in[20];
    const float* cls_b     = (const float*)d_in[21];

    char* ws = (char*)d_ws;
    // big region time-shared: qkv bf16 [M,768] (77MB) then act bf16 [M,1024] (103MB)
    unsigned short* big = (unsigned short*)ws; ws += (size_t)MROWS * FDIM * 2;  // 102.8MB
    float* qm  = (float*)ws;                   ws += (size_t)MROWS * NQB * 4;   // 1.6MB
    float* pe  = (float*)ws;                   ws += (size_t)SEQ * EMB * 4;
    float* feat = (float*)ws;                  ws += (size_t)MROWS * 4 * 4;     // 0.8MB
    unsigned short* hb  = (unsigned short*)ws; ws += (size_t)MROWS * EMB * 2;   // 25.7MB  (post-LN2 / embed stream)
    unsigned short* hb1 = (unsigned short*)ws; ws += (size_t)MROWS * EMB * 2;   // 25.7MB  (post-LN1 stream)
    unsigned short* ob  = (unsigned short*)ws; ws += (size_t)MROWS * EMB * 2;   // 25.7MB
    unsigned short* wb_in = (unsigned short*)ws; ws += (size_t)NBLK * 768 * EMB * 2;
    unsigned short* wb_o  = (unsigned short*)ws; ws += (size_t)NBLK * EMB * EMB * 2;
    unsigned short* wb_l2 = (unsigned short*)ws; ws += (size_t)NBLK * EMB * FDIM * 2;
    float* l1wT = (float*)ws;                  ws += (size_t)NBLK * NQB * FDIM * 4;

    unsigned short* qkvb = big;
    unsigned short* act  = big;

    pe_kernel<<<SEQ, EMB, 0, stream>>>(pe);
    {
        int n1 = NBLK * 768 * EMB;
        int n2 = NBLK * EMB * EMB;
        int n3 = NBLK * EMB * FDIM;
        cvt_kernel<<<n1 / 1024, 256, 0, stream>>>(in_proj_w, wb_in, n1);
        cvt_kernel<<<n2 / 1024, 256, 0, stream>>>(out_w,     wb_o,  n2);
        cvt_kernel<<<n3 / 1024, 256, 0, stream>>>(l2_w,      wb_l2, n3);
        l1t_kernel<<<(NBLK * FDIM * NQB) / 256, 256, 0, stream>>>(l1_w, l1wT);
    }

    feat_kernel<<<(MROWS * 4) / 256, 256, 0, stream>>>(
        x, qfilter_w, qfilter_b, pw_w, pw_b, feat);
    embed2_kernel<<<MROWS / 32, 256, 0, stream>>>(
        feat, embed_w, embed_b, pe, hb);

    for (int i = 0; i < NBLK; ++i) {
        // QKV projection -> bf16 [M,768]; Q cols pre-scaled for exp2 softmax
        bgemm_kernel<<<dim3(6, MROWS / 128), 512, 0, stream>>>(
            hb, wb_in + (size_t)i * 768 * EMB, in_proj_b + i * 768,
            qkvb, MROWS, 768, EMB, 256, QSCALE);
        // MFMA flash attention (bf16 in/out), register-V, HW exp2/rcp
        attn_kernel<<<BATCH * HEADS, 256, 0, stream>>>(qkvb, ob);
        // out-proj + residual(hb) + LN1 -> hb1 (+qm)
        bgemm_ln_kernel<<<MROWS / 64, 512, 0, stream>>>(
            ob, wb_o + (size_t)i * EMB * EMB, out_b + i * EMB,
            ln1_g + i * EMB, ln1_b + i * EMB, theta + i * NQB,
            hb, hb1, qm, EMB);
        // FFN activation (16 rows/block, weights in registers); act overwrites qkv
        act_kernel<<<MROWS / 16, 256, 0, stream>>>(
            qm, l1wT + (size_t)i * NQB * FDIM, l1_b + i * FDIM, act);
        // FFN l2 + residual(hb1) + LN2 -> hb (next layer's stream)
        bgemm_ln_kernel<<<MROWS / 64, 512, 0, stream>>>(
            act, wb_l2 + (size_t)i * EMB * FDIM, l2_b + i * EMB,
            ln2_g + i * EMB, ln2_b + i * EMB, nullptr,
            hb1, hb, nullptr, FDIM);
    }

    pool_cls_kernel<<<BATCH, EMB, 0, stream>>>(hb, cls_w, cls_b, (float*)d_out);
}